// Round 8
// baseline (337.490 us; speedup 1.0000x reference)
//
#include <hip/hip_runtime.h>
#include <hip/hip_bf16.h>
#include <stdint.h>

typedef _Float16 f16;
typedef __attribute__((ext_vector_type(8))) _Float16 f16x8;
typedef __attribute__((ext_vector_type(4))) _Float16 f16x4;
typedef __attribute__((ext_vector_type(2))) __fp16 fp16x2;
typedef __attribute__((ext_vector_type(4))) float f32x4;

__device__ __forceinline__ void g2l16(const void* g, void* l) {
  __builtin_amdgcn_global_load_lds(
      (const __attribute__((address_space(1))) uint32_t*)g,
      (__attribute__((address_space(3))) uint32_t*)l, 16, 0, 0);
}

__device__ __forceinline__ uint32_t pkrtz(float a, float b) {
  union { fp16x2 h; uint32_t u; } z;
  z.h = __builtin_amdgcn_cvt_pkrtz(a, b);
  return z.u;
}

// ---------------- fused weight transpose + fp32->f16 convert (all 6 weights) ----------------
__global__ __launch_bounds__(256)
void wconv_all_kernel(const float* __restrict__ Wq, const float* __restrict__ Wk,
                      const float* __restrict__ Wv, const float* __restrict__ Wp,
                      const float* __restrict__ Wfc, const float* __restrict__ Wmp,
                      f16* __restrict__ Dq, f16* __restrict__ Dk, f16* __restrict__ Dv,
                      f16* __restrict__ Dp, f16* __restrict__ Dfc, f16* __restrict__ Dmp)
{
  __shared__ float tile[32][33];
  int id = blockIdx.x;
  const float* W; f16* Wt; int K, N, local;
  if      (id < 1024) { W = Wq;  Wt = Dq;  K = 1024; N = 1024; local = id; }
  else if (id < 2048) { W = Wk;  Wt = Dk;  K = 1024; N = 1024; local = id - 1024; }
  else if (id < 3072) { W = Wv;  Wt = Dv;  K = 1024; N = 1024; local = id - 2048; }
  else if (id < 4096) { W = Wp;  Wt = Dp;  K = 1024; N = 1024; local = id - 3072; }
  else if (id < 8192) { W = Wfc; Wt = Dfc; K = 1024; N = 4096; local = id - 4096; }
  else                { W = Wmp; Wt = Dmp; K = 4096; N = 1024; local = id - 8192; }
  int ntx = N >> 5;
  int n0 = (local % ntx) * 32, k0 = (local / ntx) * 32;
  int tx = threadIdx.x & 31, ty = threadIdx.x >> 5;
#pragma unroll
  for (int i = 0; i < 4; ++i)
    tile[ty + 8*i][tx] = W[(size_t)(k0 + ty + 8*i) * N + (n0 + tx)];
  __syncthreads();
#pragma unroll
  for (int i = 0; i < 4; ++i)
    Wt[(size_t)(n0 + ty + 8*i) * K + (k0 + tx)] = (f16)tile[tx][ty + 8*i];
}

// ---------------- scaled = x*lr + x0*lx ; pre = rmsnorm(scaled) ----------------
__global__ __launch_bounds__(256)
void scale_rms_kernel(const float* __restrict__ x, const float* __restrict__ x0,
                      const float* __restrict__ lamR, const float* __restrict__ lamX,
                      float* __restrict__ scaled, f16* __restrict__ pre)
{
  const int C = 1024;
  int row = blockIdx.x, tid = threadIdx.x;
  float lr = lamR[0], lx = lamX[0];
  size_t base = (size_t)row * C;
  float4 xv = ((const float4*)(x + base))[tid];
  float4 zv = ((const float4*)(x0 + base))[tid];
  float4 sv;
  sv.x = xv.x*lr + zv.x*lx;  sv.y = xv.y*lr + zv.y*lx;
  sv.z = xv.z*lr + zv.z*lx;  sv.w = xv.w*lr + zv.w*lx;
  float ss = sv.x*sv.x + sv.y*sv.y + sv.z*sv.z + sv.w*sv.w;
#pragma unroll
  for (int off = 32; off >= 1; off >>= 1) ss += __shfl_xor(ss, off);
  __shared__ float red[4];
  if ((tid & 63) == 0) red[tid >> 6] = ss;
  __syncthreads();
  float tot = red[0] + red[1] + red[2] + red[3];
  float rs = rsqrtf(tot * (1.0f / 1024.0f) + 1e-5f);
  ((float4*)(scaled + base))[tid] = sv;
  f16* p = pre + base + tid * 4;
  p[0] = (f16)(sv.x * rs); p[1] = (f16)(sv.y * rs);
  p[2] = (f16)(sv.z * rs); p[3] = (f16)(sv.w * rs);
}

// ---------------- combine_rms: scaled2 = resid+p0+p1 (f16 partials) ; pre2 = rms ----------------
__global__ __launch_bounds__(256)
void combine_rms_kernel(const float* __restrict__ resid, const f16* __restrict__ p0,
                        const f16* __restrict__ p1, float* __restrict__ scaled2,
                        f16* __restrict__ pre2)
{
  const int C = 1024;
  int row = blockIdx.x, tid = threadIdx.x;
  size_t base = (size_t)row * C;
  float4 rv = ((const float4*)(resid + base))[tid];
  f16x4 av = ((const f16x4*)(p0 + base))[tid];
  f16x4 bv = ((const f16x4*)(p1 + base))[tid];
  float4 sv;
  sv.x = rv.x + (float)av[0] + (float)bv[0];
  sv.y = rv.y + (float)av[1] + (float)bv[1];
  sv.z = rv.z + (float)av[2] + (float)bv[2];
  sv.w = rv.w + (float)av[3] + (float)bv[3];
  float ss = sv.x*sv.x + sv.y*sv.y + sv.z*sv.z + sv.w*sv.w;
#pragma unroll
  for (int off = 32; off >= 1; off >>= 1) ss += __shfl_xor(ss, off);
  __shared__ float red[4];
  if ((tid & 63) == 0) red[tid >> 6] = ss;
  __syncthreads();
  float tot = red[0] + red[1] + red[2] + red[3];
  float rs = rsqrtf(tot * (1.0f / 1024.0f) + 1e-5f);
  ((float4*)(scaled2 + base))[tid] = sv;
  f16* p = pre2 + base + tid * 4;
  p[0] = (f16)(sv.x * rs); p[1] = (f16)(sv.y * rs);
  p[2] = (f16)(sv.z * rs); p[3] = (f16)(sv.w * rs);
}

// ---------------- combine_out: out = resid + sum of 4 f16 partials ----------------
__global__ __launch_bounds__(256)
void combine_out4_kernel(const float* __restrict__ resid, const f16* __restrict__ parts,
                         size_t pstride, float* __restrict__ out)
{
  size_t i = (size_t)blockIdx.x * 256 + threadIdx.x;
  float4 rv = ((const float4*)resid)[i];
  float4 sv = rv;
#pragma unroll
  for (int z = 0; z < 4; ++z) {
    f16x4 av = ((const f16x4*)(parts + z * pstride))[i];
    sv.x += (float)av[0]; sv.y += (float)av[1];
    sv.z += (float)av[2]; sv.w += (float)av[3];
  }
  ((float4*)out)[i] = sv;
}

// ---------------- legacy 128x128 GEMM (kept for proj, small N) ----------------
template<int EPI>
__global__ __launch_bounds__(256)
void gemm_kernel(const f16* __restrict__ A, const f16* __restrict__ Bt,
                 void* __restrict__ out, int M, int N, int K, int nb, int zb)
{
  __shared__ __align__(16) f16 smem[4 * 128 * 32];   // As0|As1|Bs0|Bs1
  const int tid = threadIdx.x;
  const int wave = tid >> 6, lane = tid & 63;
  const int col = lane & 15, quad = lane >> 4;
  const int id = blockIdx.x;
  const int xcd = id & 7, s = id >> 3;
  const int n_i = s % nb;
  const int p = s / nb;
  const int mpx = (M >> 7) >> 3;
  const int zz = p / mpx;
  const int m_i = xcd * mpx + (p % mpx);
  const int m0 = m_i * 128, n0 = n_i * 128;
  const int wm = (wave >> 1) * 64, wn = (wave & 1) * 64;
  const int Ksub = K / zb;
  const int kBeg = zz * Ksub;
  const int nIter = Ksub >> 5;
  f32x4 acc[4][4] = {};

  const size_t rowb = (size_t)K * 2;
  const char* Agp = (const char*)A  + (size_t)m0 * rowb;
  const char* Bgp = (const char*)Bt + (size_t)n0 * rowb;

  const int r_st = (tid >> 2);
  const int cb_st = (tid & 3) << 4;
  const int lb0 = (wave * 64) << 4;
  const int lb1 = (256 + wave * 64) << 4;

#define STAGE(buf, k0)                                                           \
  {                                                                              \
    const size_t koff = (size_t)(k0) * 2;                                        \
    g2l16(Agp + (size_t)r_st * rowb + koff + cb_st,                              \
          (char*)smem + (buf) * 8192 + lb0);                                     \
    g2l16(Agp + (size_t)(r_st + 64) * rowb + koff + cb_st,                       \
          (char*)smem + (buf) * 8192 + lb1);                                     \
    g2l16(Bgp + (size_t)r_st * rowb + koff + cb_st,                              \
          (char*)smem + 16384 + (buf) * 8192 + lb0);                             \
    g2l16(Bgp + (size_t)(r_st + 64) * rowb + koff + cb_st,                       \
          (char*)smem + 16384 + (buf) * 8192 + lb1);                             \
  }

  STAGE(0, kBeg)
  for (int kt = 0; kt < nIter; ++kt) {
    __syncthreads();
    if (kt + 1 < nIter) STAGE((kt + 1) & 1, kBeg + (kt + 1) * 32)
    const f16* As = smem + (kt & 1) * 4096;
    const f16* Bs = smem + 8192 + (kt & 1) * 4096;
    f16x8 af[4], bf[4];
#pragma unroll
    for (int t = 0; t < 4; ++t)
      af[t] = *(const f16x8*)(As + (wm + t*16 + col) * 32 + quad * 8);
#pragma unroll
    for (int t = 0; t < 4; ++t)
      bf[t] = *(const f16x8*)(Bs + (wn + t*16 + col) * 32 + quad * 8);
#pragma unroll
    for (int mt = 0; mt < 4; ++mt)
#pragma unroll
      for (int nt = 0; nt < 4; ++nt)
        acc[mt][nt] = __builtin_amdgcn_mfma_f32_16x16x32_f16(af[mt], bf[nt], acc[mt][nt], 0, 0, 0);
  }
#undef STAGE
  f16* ep = smem + wave * 1024;
  f16* outz = (EPI == 4) ? ((f16*)out + (size_t)zz * M * N) : (f16*)out;
#pragma unroll
  for (int mt = 0; mt < 4; ++mt) {
#pragma unroll
    for (int nt = 0; nt < 4; ++nt) {
#pragma unroll
      for (int r = 0; r < 4; ++r) {
        float v = acc[mt][nt][r];
        if (EPI == 1) { float tv = v > 0.0f ? v : 0.0f; v = tv * tv; }
        ep[(quad * 4 + r) * 64 + ((nt ^ quad) * 16 + col)] = (f16)v;
      }
    }
#pragma unroll
    for (int j = 0; j < 2; ++j) {
      int e = j * 64 + lane;
      int row = e >> 3, rb = e & 7;
      int phys16 = (((rb >> 1) ^ (row >> 2)) << 1) + (rb & 1);
      f16x8 vv = *(const f16x8*)(ep + row * 64 + phys16 * 8);
      int grow = m0 + wm + mt * 16 + row;
      int gcol = n0 + wn + rb * 8;
      *(f16x8*)(outz + (size_t)grow * N + gcol) = vv;
    }
  }
}

// ============ 256x256 8-wave GEMM, BK=32, 4 LDS buffers, prefetch distance 3 ============
// Per K-tile t: gate vmcnt(8) [tile t landed; t+1,t+2 in flight] -> barrier ->
// STAGE tile t+3 into buf (t+3)&3 (== buf (t-1)&3, freed by iter t-1's end barrier;
// issued after this iter's start barrier so every wave has passed it -> race-free) ->
// ds_read buf t&3 + 32 MFMA -> lgkmcnt(0) -> barrier.
// Buffer: A 16KB (row*64B, 4 slots of 16B) | B 16KB. Naturally conflict-free:
// bank = 16*(row&1) + 4*quad spreads a wave's b128 at the 8-bank-cycle minimum.
__device__ __forceinline__ void stage32(const char* Agp, const char* Bgp, size_t rowb,
                                        char* lds, int r0s, int sl16, size_t koff, int tid)
{
  g2l16(Agp + (size_t)r0s * rowb + koff + sl16,         lds + tid * 16);
  g2l16(Agp + (size_t)(r0s + 128) * rowb + koff + sl16, lds + 8192 + tid * 16);
  g2l16(Bgp + (size_t)r0s * rowb + koff + sl16,         lds + 16384 + tid * 16);
  g2l16(Bgp + (size_t)(r0s + 128) * rowb + koff + sl16, lds + 24576 + tid * 16);
}

template<int EPI>
__global__ __launch_bounds__(512, 2)
void gemm256_kernel(const f16* __restrict__ A, const f16* __restrict__ Bt,
                    void* __restrict__ out, int M, int N, int K, int nb, int zb)
{
  __shared__ __align__(16) f16 smem[65536];   // 128 KB = 4 x 32KB K-tile buffers
  const int tid = threadIdx.x;
  const int wave = tid >> 6, lane = tid & 63;
  const int col = lane & 15, quad = lane >> 4;
  const int id = blockIdx.x;
  const int xcd = id & 7, sb = id >> 3;
  const int n_i = sb % nb;
  const int p = sb / nb;
  const int mpx = (M >> 8) >> 3;
  const int zz = p / mpx;
  const int m_i = xcd * mpx + (p % mpx);
  const int m0 = m_i * 256, n0 = n_i * 256;
  const int wm = (wave >> 2) * 128, wn = (wave & 3) * 64;
  const int Ksub = K / zb;
  const int kBeg = zz * Ksub;
  const int nt = Ksub >> 5;                   // 32 K-tiles of BK=32
  f32x4 acc[8][4] = {};

  const size_t rowb = (size_t)K * 2;
  const char* Agp = (const char*)A  + (size_t)m0 * rowb;
  const char* Bgp = (const char*)Bt + (size_t)n0 * rowb;

  const int r0s = tid >> 2;
  const int sl16 = (tid & 3) << 4;

  stage32(Agp, Bgp, rowb, (char*)smem,         r0s, sl16, (size_t)kBeg * 2, tid);
  stage32(Agp, Bgp, rowb, (char*)smem + 32768, r0s, sl16, (size_t)(kBeg + 32) * 2, tid);
  stage32(Agp, Bgp, rowb, (char*)smem + 65536, r0s, sl16, (size_t)(kBeg + 64) * 2, tid);

  for (int t = 0; t < nt; ++t) {
    const int rem = nt - 1 - t;
    if (rem >= 2)      asm volatile("s_waitcnt vmcnt(8)" ::: "memory");
    else if (rem == 1) asm volatile("s_waitcnt vmcnt(4)" ::: "memory");
    else               asm volatile("s_waitcnt vmcnt(0)" ::: "memory");
    __builtin_amdgcn_s_barrier();
    asm volatile("" ::: "memory");

    if (t + 3 < nt)
      stage32(Agp, Bgp, rowb, (char*)smem + ((t + 3) & 3) * 32768, r0s, sl16,
              (size_t)(kBeg + (t + 3) * 32) * 2, tid);

    const f16* As = (const f16*)((const char*)smem + (t & 3) * 32768);
    const f16* Bs = As + 8192;
    f16x8 bf[4];
#pragma unroll
    for (int ct = 0; ct < 4; ++ct)
      bf[ct] = *(const f16x8*)(Bs + (wn + ct*16 + col) * 32 + quad * 8);
    __builtin_amdgcn_s_setprio(1);
#pragma unroll
    for (int mt = 0; mt < 8; ++mt) {
      f16x8 af = *(const f16x8*)(As + (wm + mt*16 + col) * 32 + quad * 8);
#pragma unroll
      for (int ct = 0; ct < 4; ++ct)
        acc[mt][ct] = __builtin_amdgcn_mfma_f32_16x16x32_f16(af, bf[ct], acc[mt][ct], 0, 0, 0);
    }
    __builtin_amdgcn_s_setprio(0);

    asm volatile("s_waitcnt lgkmcnt(0)" ::: "memory");
    __builtin_amdgcn_s_barrier();
    asm volatile("" ::: "memory");
  }

  // epilogue: all LDS free (loop ended with barrier); per-wave 16x64 slab
  f16* ep = smem + wave * 1024;
  f16* outz = (EPI == 4) ? ((f16*)out + (size_t)zz * M * N) : (f16*)out;
#pragma unroll
  for (int mt = 0; mt < 8; ++mt) {
#pragma unroll
    for (int ct = 0; ct < 4; ++ct) {
#pragma unroll
      for (int r = 0; r < 4; ++r) {
        float v = acc[mt][ct][r];
        if (EPI == 1) { float tv = v > 0.0f ? v : 0.0f; v = tv * tv; }
        ep[(quad * 4 + r) * 64 + ((ct ^ quad) * 16 + col)] = (f16)v;
      }
    }
#pragma unroll
    for (int j = 0; j < 2; ++j) {
      int e = j * 64 + lane;
      int row = e >> 3, rb = e & 7;
      int phys16 = (((rb >> 1) ^ (row >> 2)) << 1) + (rb & 1);
      f16x8 vv = *(const f16x8*)(ep + row * 64 + phys16 * 8);
      int grow = m0 + wm + mt * 16 + row;
      int gcol = n0 + wn + rb * 8;
      *(f16x8*)(outz + (size_t)grow * N + gcol) = vv;
    }
  }
}

// ---------------- fused QKV GEMM + RoPE + rmsnorm epilogue (BK=32 pipeline) ----------------
__global__ __launch_bounds__(512, 2)
void gemm256_qkv_kernel(const f16* __restrict__ A, const f16* __restrict__ Bt,
                        f16* __restrict__ qb, f16* __restrict__ kbuf, f16* __restrict__ vtg,
                        const float* __restrict__ cs, const float* __restrict__ sn)
{
  const int K = 1024, nb = 12, nt = 32;
  __shared__ __align__(16) f16 smem[65536];
  const int tid = threadIdx.x;
  const int wave = tid >> 6, lane = tid & 63;
  const int col = lane & 15, quad = lane >> 4;
  const int id = blockIdx.x;
  const int xcd = id & 7, sb = id >> 3;
  const int n_i = sb % nb;
  const int m_i = xcd * 2 + (sb / nb);
  const int m0 = m_i * 256, n0 = n_i * 256;
  const int wm = (wave >> 2) * 128, wn = (wave & 3) * 64;
  f32x4 acc[8][4] = {};

  const size_t rowb = (size_t)K * 2;
  const char* Agp = (const char*)A  + (size_t)m0 * rowb;
  const char* Bgp = (const char*)Bt + (size_t)n0 * rowb;

  const int r0s = tid >> 2;
  const int sl16 = (tid & 3) << 4;

  stage32(Agp, Bgp, rowb, (char*)smem,         r0s, sl16, 0, tid);
  stage32(Agp, Bgp, rowb, (char*)smem + 32768, r0s, sl16, (size_t)32 * 2, tid);
  stage32(Agp, Bgp, rowb, (char*)smem + 65536, r0s, sl16, (size_t)64 * 2, tid);

  for (int t = 0; t < nt; ++t) {
    const int rem = nt - 1 - t;
    if (rem >= 2)      asm volatile("s_waitcnt vmcnt(8)" ::: "memory");
    else if (rem == 1) asm volatile("s_waitcnt vmcnt(4)" ::: "memory");
    else               asm volatile("s_waitcnt vmcnt(0)" ::: "memory");
    __builtin_amdgcn_s_barrier();
    asm volatile("" ::: "memory");

    if (t + 3 < nt)
      stage32(Agp, Bgp, rowb, (char*)smem + ((t + 3) & 3) * 32768, r0s, sl16,
              (size_t)((t + 3) * 32) * 2, tid);

    const f16* As = (const f16*)((const char*)smem + (t & 3) * 32768);
    const f16* Bs = As + 8192;
    f16x8 bf[4];
#pragma unroll
    for (int ct = 0; ct < 4; ++ct)
      bf[ct] = *(const f16x8*)(Bs + (wn + ct*16 + col) * 32 + quad * 8);
    __builtin_amdgcn_s_setprio(1);
#pragma unroll
    for (int mt = 0; mt < 8; ++mt) {
      f16x8 af = *(const f16x8*)(As + (wm + mt*16 + col) * 32 + quad * 8);
#pragma unroll
      for (int ct = 0; ct < 4; ++ct)
        acc[mt][ct] = __builtin_amdgcn_mfma_f32_16x16x32_f16(af, bf[ct], acc[mt][ct], 0, 0, 0);
    }
    __builtin_amdgcn_s_setprio(0);

    asm volatile("s_waitcnt lgkmcnt(0)" ::: "memory");
    __builtin_amdgcn_s_barrier();
    asm volatile("" ::: "memory");
  }

  const int cw = n0 + wn;          // wave's 64-col base in 0..3071
  const int sel = cw >> 10;        // 0: Q, 1: K, 2: V (wave-uniform)
  if (sel < 2) {
    f16* dst = (sel == 0) ? qb : kbuf;
    const int cbase = cw & 1023;
    f16* ep = smem + wave * 1024;
#pragma unroll
    for (int mt = 0; mt < 8; ++mt) {
      // RoPE + rmsnorm on acc[mt]: rotate-half partner of d=ct*16+col is
      // d^32=(ct^2)*16+col -> same lane, register ct^2; rms via 16-lane shfl reduce.
#pragma unroll
      for (int r = 0; r < 4; ++r) {
        const int t = (m0 + wm + mt * 16 + quad * 4 + r) & 2047;
        const float* cp = cs + t * 64 + col;
        const float* sp = sn + t * 64 + col;
        float yv[4];
        float ss = 0.f;
#pragma unroll
        for (int ct = 0; ct < 4; ++ct) {
          float c = cp[ct * 16], s = sp[ct * 16];
          float rot = acc[mt][ct ^ 2][r];
          float y = acc[mt][ct][r] * c + (ct < 2 ? -rot : rot) * s;
          yv[ct] = y;
          ss += y * y;
        }
        ss += __shfl_xor(ss, 1, 16);
        ss += __shfl_xor(ss, 2, 16);
        ss += __shfl_xor(ss, 4, 16);
        ss += __shfl_xor(ss, 8, 16);
        float rs = rsqrtf(ss * (1.0f / 64.0f) + 1e-5f);
#pragma unroll
        for (int ct = 0; ct < 4; ++ct) acc[mt][ct][r] = yv[ct] * rs;
      }
#pragma unroll
      for (int ct = 0; ct < 4; ++ct)
#pragma unroll
        for (int r = 0; r < 4; ++r)
          ep[(quad * 4 + r) * 64 + ((ct ^ quad) * 16 + col)] = (f16)acc[mt][ct][r];
#pragma unroll
      for (int j = 0; j < 2; ++j) {
        int e = j * 64 + lane;
        int row = e >> 3, rb = e & 7;
        int phys16 = (((rb >> 1) ^ (row >> 2)) << 1) + (rb & 1);
        f16x8 vv = *(const f16x8*)(ep + row * 64 + phys16 * 8);
        int grow = m0 + wm + mt * 16 + row;
        *(f16x8*)(dst + (size_t)grow * 1024 + cbase + rb * 8) = vv;
      }
    }
  } else {
    // V: acc[mt][ct][0..3] are 4 consecutive t (rows), same output d -> direct 8B store
#pragma unroll
    for (int mt = 0; mt < 8; ++mt) {
      int t0 = m0 + wm + mt * 16 + quad * 4;
      int b = t0 >> 11, t = t0 & 2047;
#pragma unroll
      for (int ct = 0; ct < 4; ++ct) {
        int dd = (cw & 1023) + ct * 16 + col;   // 0..1023 -> h = dd>>6, d = dd&63
        int hh = dd >> 6, d = dd & 63;
        f16x4 vv;
#pragma unroll
        for (int r = 0; r < 4; ++r) vv[r] = (f16)acc[mt][ct][r];
        *(f16x4*)(vtg + ((size_t)((b * 16 + hh) * 64 + d)) * 2048 + t) = vv;
      }
    }
  }
}

// ---------------- causal flash attention v7: paired q-tiles + in-register P ----------------
__global__ __launch_bounds__(512)
void attn_kernel(const f16* __restrict__ Q, const f16* __restrict__ Kc,
                 const f16* __restrict__ Vt, f16* __restrict__ O)
{
  const int T = 2048, C = 1024;
  __shared__ __align__(16) f16 Ks[2][64 * 64];
  __shared__ __align__(16) f16 Vs[2][64 * 64];
  const int tid = threadIdx.x, wave = tid >> 6, lane = tid & 63;
  const int col = lane & 15, quad = lane >> 4;
  const int bh = blockIdx.x, b = bh >> 4, h = bh & 15;
  const int pr = blockIdx.y;                  // 0..15
  const int grp = wave >> 2;                  // 0: hi tile, 1: lo tile
  const int w4 = wave & 3;
  const int hiB = 31 - pr;
  const int myB = grp ? pr : hiB;             // causal bound (inclusive) == q-tile idx
  const int q0 = myB * 64;

  const f16* qb = Q  + ((size_t)b * T) * C + h * 64;
  const f16* kb = Kc + ((size_t)b * T) * C + h * 64;
  const f16* vb = Vt + ((size_t)bh * 64) * T;

  f16x8 bq[2];
#pragma unroll
  for (int ks = 0; ks < 2; ++ks)
    bq[ks] = *(const f16x8*)(qb + (size_t)(q0 + w4*16 + col) * C + ks*32 + quad*8);

  f32x4 o_acc[4];
#pragma unroll
  for (int dt = 0; dt < 4; ++dt) o_acc[dt] = (f32x4){0.f,0.f,0.f,0.f};
  float l_acc = 0.f;

  const int srow = lane >> 3;
  const int sblk = (lane & 7) ^ srow;
  const int r0 = wave * 8;

  g2l16(kb + (size_t)(r0 + srow) * C + sblk * 8, (char*)Ks[0] + r0 * 128);
  g2l16(vb + (size_t)(r0 + srow) * T + sblk * 8, (char*)Vs[0] + r0 * 128);

  const int cm = col & 7;
  const int c00 = quad,            c01 = 4 + (quad ^ 1);
  const int c10 = 8 + (quad ^ 2),  c11 = 12 + (quad ^ 3);
  const int o00 = (((c00 >> 1) ^ cm) << 3) + ((c00 & 1) << 2);
  const int o01 = (((c01 >> 1) ^ cm) << 3) + ((c01 & 1) << 2);
  const int o10 = (((c10 >> 1) ^ cm) << 3) + ((c10 & 1) << 2);
  const int o11 = (((c11 >> 1) ^ cm) << 3) + ((c11 & 1) << 2);

  int cur = 0;
  for (int kt = 0; kt <= hiB; ++kt) {
    __syncthreads();

    if (kt < hiB) {
      const int ks1 = (kt + 1) * 64;
      g2l16(kb + (size_t)(ks1 + r0 + srow) * C + sblk * 8, (char*)Ks[cur ^ 1] + r0 * 128);
      g2l16(vb + (size_t)(r0 + srow) * T + ks1 + sblk * 8, (char*)Vs[cur ^ 1] + r0 * 128);
    }

    if (kt <= myB) {
      f32x4 s[4];
#pragma unroll
      for (int nt = 0; nt < 4; ++nt) s[nt] = (f32x4){0.f,0.f,0.f,0.f};
      __builtin_amdgcn_s_setprio(1);
#pragma unroll
      for (int ks = 0; ks < 2; ++ks) {
#pragma unroll
        for (int nt = 0; nt < 4; ++nt) {
          int key = nt * 16 + col;
          f16x8 ak = *(const f16x8*)(Ks[cur] + key * 64 + (((ks*4 + quad) ^ (key & 7)) * 8));
          s[nt] = __builtin_amdgcn_mfma_f32_16x16x32_f16(ak, bq[ks], s[nt], 0, 0, 0);
        }
      }
      __builtin_amdgcn_s_setprio(0);

      const bool masked = (kt == myB);
      const int qloc = w4 * 16 + col;
      uint32_t pk[4][2];
      float l_tile = 0.f;
#pragma unroll
      for (int nt = 0; nt < 4; ++nt) {
        float p[4];
#pragma unroll
        for (int r = 0; r < 4; ++r) {
          float pv = __expf(s[nt][r] * 0.125f);
          if (masked && (nt * 16 + quad * 4 + r > qloc)) pv = 0.0f;
          p[r] = pv;
        }
        l_tile += (p[0] + p[1]) + (p[2] + p[3]);
        pk[nt][0] = pkrtz(p[0], p[1]);
        pk[nt][1] = pkrtz(p[2], p[3]);
      }
      l_acc += l_tile;

      union { uint32_t u[4]; f16x8 v; } pa0, pa1;
      pa0.u[0] = pk[0][0];
      pa0.u[1] = pk[0][1];
      pa0.u[2] = (uint32_t)__shfl_xor((int)pk[1][0], 16);
      pa0.u[3] = (uint32_t)__shfl_xor((int)pk[1][1], 16);
      pa1.u[0] = (uint32_t)__shfl_xor((int)pk[2][0], 32);
      pa1.u[1] = (uint32_t)__shfl_xor((int)pk[2][1], 32);
      pa1.u[2] = (uint32_t)__shfl_xor((int)pk[3][0], 48);
      pa1.u[3] = (uint32_t)__shfl_xor((int)pk[3][1], 48);

      __builtin_amdgcn_s_setprio(1);
#pragma unroll
      for (int dt = 0; dt < 4; ++dt) {
        const f16* vrow = Vs[cur] + (dt * 16 + col) * 64;
        union { struct { f16x4 lo, hi; } p; f16x8 v; } bv0, bv1;
        bv0.p.lo = *(const f16x4*)(vrow + o00);
        bv0.p.hi = *(const f16x4*)(vrow + o01);
        bv1.p.lo = *(const f16x4*)(vrow + o10);
        bv1.p.hi = *(const f16x4*)(vrow + o11);
        o_acc[dt] = __builtin_amdgcn_mfma_f32_16x16x32_f16(pa0.v, bv0.v, o_acc[dt], 0, 0, 0);
        o_acc[dt] = __builtin_amdgcn_mfma_f32_16x16x32_f16(pa1.v, bv1.v, o_acc[dt], 0, 0, 0);
      }
      __builtin_amdgcn_s_setprio(0);
    }
    cur ^= 1;
  }

  l_acc += __shfl_xor(l_acc, 16);
  l_acc += __shfl_xor(l_acc, 32);
  float linv[4];
#pragma unroll
  for (int r = 0; r < 4; ++r)
    linv[r] = 1.0f / __shfl(l_acc, (wave & 4) * 16 + quad * 4 + r, 64);

#pragma unroll
  for (int dt = 0; dt < 4; ++dt) {
#pragma unroll
    for (int r = 0; r < 4; ++r) {
      int qr = q0 + w4 * 16 + quad * 4 + r;
      float v = o_acc[dt][r] * linv[r];
      O[((size_t)b * T + qr) * C + h * 64 + dt * 16 + col] = (f16)v;
    }
  }
}

// ---------------- orchestration ----------------
extern "C" void kernel_launch(void* const* d_in, const int* in_sizes, int n_in,
                              void* d_out, int out_size, void* d_ws, size_t ws_size,
                              hipStream_t stream)
{
  const float* x    = (const float*)d_in[0];
  const float* x0   = (const float*)d_in[1];
  const float* lamR = (const float*)d_in[2];
  const float* lamX = (const float*)d_in[3];
  const float* cs   = (const float*)d_in[4];
  const float* sn   = (const float*)d_in[5];
  const float* Wq   = (const float*)d_in[6];
  const float* Wk   = (const float*)d_in[7];
  const float* Wv   = (const float*)d_in[8];
  const float* Wp   = (const float*)d_in[9];
  const float* Wfc  = (const float*)d_in[10];
  const float* Wmp  = (const float*)d_in[11];
  float* out = (float*)d_out;

  const int B = 2, T = 2048, C = 1024, H = 16;
  const int M = B * T;  // 4096
  const size_t MB = 1ull << 20;
  char* ws = (char*)d_ws;
  f16*   Wqkv_t = (f16*)(ws + 0 * MB);     // 6 MB
  f16*   Wp_t   = (f16*)(ws + 6 * MB);     // 2 MB
  f16*   Wfc_t  = (f16*)(ws + 8 * MB);     // 8 MB
  f16*   Wmp_t  = (f16*)(ws + 16 * MB);    // 8 MB
  float* scaled  = (float*)(ws + 24 * MB); // 16 MB fp32 [later: mlp partials z0,z1]
  f16*   pre     = (f16*)(ws + 40 * MB);   // 8 MB       [later: attnOut]
  f16*   qb      = (f16*)(ws + 48 * MB);   // 8 MB       [later: pre2]
  f16*   kbuf    = (f16*)(ws + 56 * MB);   // 8 MB
  f16*   vtg     = (f16*)(ws + 64 * MB);   // 8 MB V^T
  float* scaled2 = (float*)(ws + 72 * MB); // 16 MB fp32
  f16*   hbuf    = (f16*)(ws + 88 * MB);   // 32 MB      [first: proj f16 partials 2x8MB]
  f16*   attnOut = pre;
  f16*   pre2    = qb;
  f16*   projP   = (f16*)(ws + 88 * MB);   // 2 x 8 MB f16 (before hbuf written)
  f16*   mlpP    = (f16*)(ws + 24 * MB);   // 4 x 8 MB f16 (scaled/pre/qb all dead)

  dim3 tb(256);
  dim3 tb5(512);
  wconv_all_kernel<<<dim3(12288), tb, 0, stream>>>(
      Wq, Wk, Wv, Wp, Wfc, Wmp,
      Wqkv_t, Wqkv_t + 1024*1024, Wqkv_t + 2048*1024, Wp_t, Wfc_t, Wmp_t);

  scale_rms_kernel<<<M, tb, 0, stream>>>(x, x0, lamR, lamX, scaled, pre);

  // fused QKV GEMM + RoPE + rms: 256^2 tiles, BK=32 distance-3 pipeline, 192 blocks
  gemm256_qkv_kernel<<<dim3(192), tb5, 0, stream>>>(pre, Wqkv_t, qb, kbuf, vtg, cs, sn);

  // paired-causal attention: (bh, pair) grid, 512 uniform blocks, 8 waves
  attn_kernel<<<dim3(B * H, 16), tb5, 0, stream>>>(qb, kbuf, vtg, attnOut);

  // proj GEMM split-K=2 (512 blocks, legacy 128^2) -> f16 partials ; combine + rms
  gemm_kernel<4><<<dim3(8 * 32 * 2), tb, 0, stream>>>(attnOut, Wp_t, projP, M, C, C, 8, 2);
  combine_rms_kernel<<<M, tb, 0, stream>>>(scaled, projP, projP + (size_t)M*C, scaled2, pre2);

  // fc GEMM + relu^2: 256^2 tiles, BK=32 pipeline, 256 blocks
  gemm256_kernel<1><<<dim3(256), tb5, 0, stream>>>(pre2, Wfc_t, hbuf, M, 4*C, C, 16, 1);

  // mlp proj split-K=4: 256^2 tiles, BK=32 pipeline, 256 blocks -> f16 partials ; combine
  gemm256_kernel<4><<<dim3(256), tb5, 0, stream>>>(hbuf, Wmp_t, mlpP, M, C, 4*C, 4, 4);
  combine_out4_kernel<<<(M*C)/1024, tb, 0, stream>>>(scaled2, mlpP, (size_t)M*C, out);
}